// Round 1
// baseline (831.674 us; speedup 1.0000x reference)
//
#include <hip/hip_runtime.h>

#define B_ 2048
#define L_ 200
#define D_ 128
#define NITEMS 50000

// ---------------- reduction helpers ----------------
__device__ __forceinline__ float wave_sum(float v) {
#pragma unroll
    for (int m = 32; m >= 1; m >>= 1) v += __shfl_xor(v, m, 64);
    return v;
}
__device__ __forceinline__ float wave_max(float v) {
#pragma unroll
    for (int m = 32; m >= 1; m >>= 1) v = fmaxf(v, __shfl_xor(v, m, 64));
    return v;
}
__device__ __forceinline__ float bsum256(float v, float* red) {
    v = wave_sum(v);
    __syncthreads();
    if ((threadIdx.x & 63) == 0) red[threadIdx.x >> 6] = v;
    __syncthreads();
    return red[0] + red[1] + red[2] + red[3];
}
__device__ __forceinline__ float bmax256(float v, float* red) {
    v = wave_max(v);
    __syncthreads();
    if ((threadIdx.x & 63) == 0) red[threadIdx.x >> 6] = v;
    __syncthreads();
    return fmaxf(fmaxf(red[0], red[1]), fmaxf(red[2], red[3]));
}
__device__ __forceinline__ float bsum128(float v, float* red) {
    v = wave_sum(v);
    __syncthreads();
    if ((threadIdx.x & 63) == 0) red[threadIdx.x >> 6] = v;
    __syncthreads();
    return red[0] + red[1];
}

// ---------------- K1: M = Wk @ W_h  (M[e][c] = sum_d Wk[e][d]*W_h[d][c]) ----------------
__global__ __launch_bounds__(128) void k1_M(const float* __restrict__ Wk,
                                            const float* __restrict__ Wh,
                                            float* __restrict__ M) {
    __shared__ float wk[128];
    const int e = blockIdx.x, c = threadIdx.x;
    wk[c] = Wk[e * 128 + c];
    __syncthreads();
    float s = 0.f;
#pragma unroll 4
    for (int d = 0; d < 128; ++d) s += wk[d] * Wh[d * 128 + c];
    M[e * 128 + c] = s;
}

// ---------------- K2: per-b prep ----------------
__global__ __launch_bounds__(128) void k2_prep(
    const int* __restrict__ user_idx, const int* __restrict__ item_idx,
    const int* __restrict__ user_hist, const float* __restrict__ user_embed,
    const float* __restrict__ item_embed, const float* __restrict__ W_i,
    const float* __restrict__ Wq, float* __restrict__ uid_o,
    float* __restrict__ tid_o, float* __restrict__ qu_o, float* __restrict__ qt_o,
    int* __restrict__ hist_o, float* __restrict__ maskf_o) {
    const int b = blockIdx.x, t = threadIdx.x;
    const int ui = user_idx[b], ii = item_idx[b];
    __shared__ float uid_s[128], traw_s[128], tid_s[128];
    const float uv = user_embed[(long)ui * 128 + t];
    const float tv = item_embed[(long)ii * 128 + t];
    uid_s[t] = uv;
    traw_s[t] = tv;
    uid_o[b * 128 + t] = uv;
    for (int l = t; l < L_; l += 128) {
        const int hv = user_hist[(long)ui * L_ + l];
        hist_o[b * L_ + l] = hv;
        maskf_o[b * L_ + l] = (hv != ii && hv != NITEMS) ? 1.f : 0.f;
    }
    __syncthreads();
    float tidv = 0.f, quv = 0.f;
#pragma unroll 2
    for (int c = 0; c < 128; c += 4) {
        const float4 wi = *reinterpret_cast<const float4*>(&W_i[t * 128 + c]);
        const float4 wq = *reinterpret_cast<const float4*>(&Wq[t * 128 + c]);
        tidv += wi.x * traw_s[c] + wi.y * traw_s[c + 1] + wi.z * traw_s[c + 2] + wi.w * traw_s[c + 3];
        quv  += wq.x * uid_s[c]  + wq.y * uid_s[c + 1]  + wq.z * uid_s[c + 2]  + wq.w * uid_s[c + 3];
    }
    tid_s[t] = tidv;
    tid_o[b * 128 + t] = tidv;
    qu_o[b * 128 + t] = quv;
    __syncthreads();
    float qtv = 0.f;
#pragma unroll 2
    for (int c = 0; c < 128; c += 4) {
        const float4 wq = *reinterpret_cast<const float4*>(&Wq[t * 128 + c]);
        qtv += wq.x * tid_s[c] + wq.y * tid_s[c + 1] + wq.z * tid_s[c + 2] + wq.w * tid_s[c + 3];
    }
    qt_o[b * 128 + t] = qtv;
}

// ---------------- K3: kw GEMM + fused score epilogue ----------------
// 64-row tile per block, 256 threads: thread (rg 0..15, eg 0..15) owns 4 rows x 8 e.
__global__ __launch_bounds__(256) void k3_scores(
    const float* __restrict__ M, const float* __restrict__ item_embed,
    const int* __restrict__ hist_g, const float* __restrict__ qu_,
    const float* __restrict__ qt_, const float* __restrict__ v_attn,
    float* __restrict__ scu, float* __restrict__ sci) {
    __shared__ float A[64][132];
    __shared__ int idx_s[64];
    const int t = threadIdx.x;
    const int rbase = blockIdx.x * 64;
    if (t < 64) idx_s[t] = hist_g[rbase + t];
    __syncthreads();
#pragma unroll
    for (int k = 0; k < 8; ++k) {
        const int v = k * 256 + t;
        const int row = v >> 5;
        const int c4 = (v & 31) << 2;
        const float4 val =
            *reinterpret_cast<const float4*>(&item_embed[(long)idx_s[row] * 128 + c4]);
        *reinterpret_cast<float4*>(&A[row][c4]) = val;
    }
    __syncthreads();
    const int rg = t >> 4, eg = t & 15;
    const int e0 = eg << 3;
    float acc[4][8];
#pragma unroll
    for (int i = 0; i < 4; ++i)
#pragma unroll
        for (int j = 0; j < 8; ++j) acc[i][j] = 0.f;

    for (int cc = 0; cc < 128; cc += 4) {
        float4 a[4];
#pragma unroll
        for (int i = 0; i < 4; ++i)
            a[i] = *reinterpret_cast<const float4*>(&A[rg * 4 + i][cc]);
#pragma unroll
        for (int j = 0; j < 8; ++j) {
            const float4 m = *reinterpret_cast<const float4*>(&M[(e0 + j) * 128 + cc]);
#pragma unroll
            for (int i = 0; i < 4; ++i)
                acc[i][j] += a[i].x * m.x + a[i].y * m.y + a[i].z * m.z + a[i].w * m.w;
        }
    }
    const float4 v0 = *reinterpret_cast<const float4*>(&v_attn[e0]);
    const float4 v1 = *reinterpret_cast<const float4*>(&v_attn[e0 + 4]);
    const float vv[8] = {v0.x, v0.y, v0.z, v0.w, v1.x, v1.y, v1.z, v1.w};
#pragma unroll
    for (int i = 0; i < 4; ++i) {
        const int r = rbase + rg * 4 + i;
        const int b = r / L_;
        const float4 qa = *reinterpret_cast<const float4*>(&qu_[b * 128 + e0]);
        const float4 qb = *reinterpret_cast<const float4*>(&qu_[b * 128 + e0 + 4]);
        const float4 ta = *reinterpret_cast<const float4*>(&qt_[b * 128 + e0]);
        const float4 tb = *reinterpret_cast<const float4*>(&qt_[b * 128 + e0 + 4]);
        const float qv[8] = {qa.x, qa.y, qa.z, qa.w, qb.x, qb.y, qb.z, qb.w};
        const float tv[8] = {ta.x, ta.y, ta.z, ta.w, tb.x, tb.y, tb.z, tb.w};
        float su = 0.f, si = 0.f;
#pragma unroll
        for (int j = 0; j < 8; ++j) {
            su += vv[j] * tanhf(qv[j] + acc[i][j]);
            si += vv[j] * tanhf(tv[j] + acc[i][j]);
        }
#pragma unroll
        for (int m = 1; m < 16; m <<= 1) {
            su += __shfl_xor(su, m, 64);
            si += __shfl_xor(si, m, 64);
        }
        if (eg == 0) {
            scu[r] = su * 0.25f;  // /TAU
            sci[r] = si * 0.25f;
        }
    }
}

// ---------------- K4: softmax + lognormal weights + KL partials ----------------
__global__ __launch_bounds__(256) void k4_softmax(
    const float* __restrict__ scu, const float* __restrict__ sci,
    const float* __restrict__ maskf, const float* __restrict__ noise_u,
    const float* __restrict__ noise_i, float* __restrict__ atu,
    float* __restrict__ ati, float* __restrict__ klu, float* __restrict__ kli,
    float* __restrict__ msm) {
    const int b = blockIdx.x, t = threadIdx.x;
    __shared__ float red[4];
    const bool act = t < L_;
    const int off = b * L_ + t;
    const float mk = act ? maskf[off] : 0.f;
    const float msum_v = bsum256(mk, red);
    if (t == 0) msm[b] = msum_v;

    const float* sc[2] = {scu, sci};
    const float* nz[2] = {noise_u, noise_i};
    float* at[2] = {atu, ati};
    float* kl[2] = {klu, kli};
#pragma unroll
    for (int side = 0; side < 2; ++side) {
        const float s = act ? (mk > 0.5f ? sc[side][off] : -1e9f) : -1e30f;
        const float mx = bmax256(s, red);
        const float e = act ? expf(s - mx) : 0.f;
        const float Z = bsum256(e, red);
        const float phi = e / Z;
        const float mu = logf(phi + 1e-8f);
        const float w = act ? expf(mu + 0.1f * nz[side][off]) * mk : 0.f;
        const float Zw = bsum256(w, red);
        if (act) at[side][off] = w / (Zw + 1e-8f);
        const float klel = act ? (2.3025850929940457f + 0.5f * (0.01f + mu * mu) - 0.5f) * mk : 0.f;
        const float kls = bsum256(klel, red);
        if (t == 0) kl[side][b] = kls;
    }
}

// ---------------- K5: attn apply + W_h matvec + LN + logit ----------------
__global__ __launch_bounds__(128) void k5_out(
    const float* __restrict__ atu, const float* __restrict__ ati,
    const int* __restrict__ hist_g, const float* __restrict__ item_embed,
    const float* __restrict__ W_h, const float* __restrict__ uid,
    const float* __restrict__ tid, const float* __restrict__ gamma_u,
    const float* __restrict__ beta_u, const float* __restrict__ gamma_i,
    const float* __restrict__ beta_i, const float* __restrict__ pred_W,
    const float* __restrict__ pred_b, float* __restrict__ out) {
    const int b = blockIdx.x, t = threadIdx.x;
    __shared__ float au[L_], ai[L_];
    __shared__ int hg[L_];
    __shared__ float aru[128], ari[128];
    __shared__ float red[2];
    for (int l = t; l < L_; l += 128) {
        au[l] = atu[b * L_ + l];
        ai[l] = ati[b * L_ + l];
        hg[l] = hist_g[b * L_ + l];
    }
    __syncthreads();
    float su = 0.f, si = 0.f;
#pragma unroll 4
    for (int l = 0; l < L_; ++l) {
        const float h = item_embed[(long)hg[l] * 128 + t];
        su += au[l] * h;
        si += ai[l] * h;
    }
    aru[t] = su;
    ari[t] = si;
    __syncthreads();
    float ou = 0.f, oi = 0.f;
#pragma unroll 2
    for (int c = 0; c < 128; c += 4) {
        const float4 w = *reinterpret_cast<const float4*>(&W_h[t * 128 + c]);
        ou += w.x * aru[c] + w.y * aru[c + 1] + w.z * aru[c + 2] + w.w * aru[c + 3];
        oi += w.x * ari[c] + w.y * ari[c + 1] + w.z * ari[c + 2] + w.w * ari[c + 3];
    }
    const float xu = ou * uid[b * 128 + t];
    const float xi = oi * tid[b * 128 + t];
    // LayerNorm u
    const float mu_ = bsum128(xu, red) * (1.f / 128.f);
    const float du = xu - mu_;
    const float vu = bsum128(du * du, red) * (1.f / 128.f);
    const float u = du * rsqrtf(vu + 1e-5f) * gamma_u[t] + beta_u[t];
    // LayerNorm i
    const float mi_ = bsum128(xi, red) * (1.f / 128.f);
    const float di = xi - mi_;
    const float vi = bsum128(di * di, red) * (1.f / 128.f);
    const float iv = di * rsqrtf(vi + 1e-5f) * gamma_i[t] + beta_i[t];
    // logit
    const float p = bsum128(u * iv * pred_W[t], red);
    if (t == 0) out[b] = p + pred_b[0];
}

// ---------------- K6: KL final reduction ----------------
__global__ __launch_bounds__(256) void k6_kl(const float* __restrict__ klu,
                                             const float* __restrict__ kli,
                                             const float* __restrict__ msm,
                                             float* __restrict__ out) {
    __shared__ float red[4];
    const int t = threadIdx.x;
    float su = 0.f, si = 0.f, sm = 0.f;
    for (int b = t; b < B_; b += 256) {
        su += klu[b];
        si += kli[b];
        sm += msm[b];
    }
    su = bsum256(su, red);
    si = bsum256(si, red);
    sm = bsum256(sm, red);
    if (t == 0) {
        const float inv = 1.f / (sm + 1e-8f);
        out[0] = 0.5f * (su * inv + si * inv);
    }
}

extern "C" void kernel_launch(void* const* d_in, const int* in_sizes, int n_in,
                              void* d_out, int out_size, void* d_ws, size_t ws_size,
                              hipStream_t stream) {
    const int* user_idx = (const int*)d_in[0];
    const int* item_idx = (const int*)d_in[1];
    const int* user_hist = (const int*)d_in[2];
    const float* user_embed = (const float*)d_in[3];
    const float* item_embed = (const float*)d_in[4];
    const float* W_i = (const float*)d_in[5];
    const float* W_h = (const float*)d_in[6];
    const float* Wq = (const float*)d_in[7];
    const float* Wk = (const float*)d_in[8];
    const float* v_attn = (const float*)d_in[9];
    const float* pred_W = (const float*)d_in[10];
    const float* pred_b = (const float*)d_in[11];
    const float* gamma_u = (const float*)d_in[12];
    const float* beta_u = (const float*)d_in[13];
    const float* gamma_i = (const float*)d_in[14];
    const float* beta_i = (const float*)d_in[15];
    const float* noise_u = (const float*)d_in[16];
    const float* noise_i = (const float*)d_in[17];
    float* out = (float*)d_out;

    char* ws = (char*)d_ws;
    size_t off = 0;
    auto alloc = [&](size_t bytes) -> void* {
        void* p = ws + off;
        off = (off + bytes + 255) & ~(size_t)255;
        return p;
    };
    float* M   = (float*)alloc(128 * 128 * 4);
    float* uid = (float*)alloc((size_t)B_ * 128 * 4);
    float* tid = (float*)alloc((size_t)B_ * 128 * 4);
    float* qu  = (float*)alloc((size_t)B_ * 128 * 4);
    float* qt  = (float*)alloc((size_t)B_ * 128 * 4);
    int* hg    = (int*)alloc((size_t)B_ * L_ * 4);
    float* mkf = (float*)alloc((size_t)B_ * L_ * 4);
    float* scu = (float*)alloc((size_t)B_ * L_ * 4);
    float* sci = (float*)alloc((size_t)B_ * L_ * 4);
    float* atu = (float*)alloc((size_t)B_ * L_ * 4);
    float* ati = (float*)alloc((size_t)B_ * L_ * 4);
    float* klu = (float*)alloc((size_t)B_ * 4);
    float* kli = (float*)alloc((size_t)B_ * 4);
    float* msm = (float*)alloc((size_t)B_ * 4);

    k1_M<<<128, 128, 0, stream>>>(Wk, W_h, M);
    k2_prep<<<B_, 128, 0, stream>>>(user_idx, item_idx, user_hist, user_embed,
                                    item_embed, W_i, Wq, uid, tid, qu, qt, hg, mkf);
    k3_scores<<<(B_ * L_) / 64, 256, 0, stream>>>(M, item_embed, hg, qu, qt, v_attn,
                                                  scu, sci);
    k4_softmax<<<B_, 256, 0, stream>>>(scu, sci, mkf, noise_u, noise_i, atu, ati,
                                       klu, kli, msm);
    k5_out<<<B_, 128, 0, stream>>>(atu, ati, hg, item_embed, W_h, uid, tid, gamma_u,
                                   beta_u, gamma_i, beta_i, pred_W, pred_b, out);
    k6_kl<<<1, 256, 0, stream>>>(klu, kli, msm, out + B_);
}

// Round 2
// 250.389 us; speedup vs baseline: 3.3215x; 3.3215x over previous
//
#include <hip/hip_runtime.h>

#define B_ 2048
#define L_ 200
#define D_ 128
#define NITEMS 50000

typedef __attribute__((ext_vector_type(8))) short short8v;
typedef __attribute__((ext_vector_type(4))) float floatx4;

// ---------------- helpers ----------------
__device__ __forceinline__ short f2bf(float f) {
    union { float f; unsigned u; } v;
    v.f = f;
    unsigned r = v.u + 0x7FFFu + ((v.u >> 16) & 1u);
    return (short)(r >> 16);
}

__device__ __forceinline__ float fast_tanh(float x) {
    x = fminf(fmaxf(x, -15.f), 15.f);
    const float t = exp2f(x * 2.885390081777927f);  // e^(2x)
    return (t - 1.f) * __builtin_amdgcn_rcpf(t + 1.f);
}

__device__ __forceinline__ float wave_sum(float v) {
#pragma unroll
    for (int m = 32; m >= 1; m >>= 1) v += __shfl_xor(v, m, 64);
    return v;
}
__device__ __forceinline__ float wave_max(float v) {
#pragma unroll
    for (int m = 32; m >= 1; m >>= 1) v = fmaxf(v, __shfl_xor(v, m, 64));
    return v;
}
__device__ __forceinline__ float bsum256(float v, float* red) {
    v = wave_sum(v);
    __syncthreads();
    if ((threadIdx.x & 63) == 0) red[threadIdx.x >> 6] = v;
    __syncthreads();
    return red[0] + red[1] + red[2] + red[3];
}
__device__ __forceinline__ float bmax256(float v, float* red) {
    v = wave_max(v);
    __syncthreads();
    if ((threadIdx.x & 63) == 0) red[threadIdx.x >> 6] = v;
    __syncthreads();
    return fmaxf(fmaxf(red[0], red[1]), fmaxf(red[2], red[3]));
}
__device__ __forceinline__ float bsum128(float v, float* red) {
    v = wave_sum(v);
    __syncthreads();
    if ((threadIdx.x & 63) == 0) red[threadIdx.x >> 6] = v;
    __syncthreads();
    return red[0] + red[1];
}

// ---------------- K1: Mbf = bf16( Wk @ W_h )  (M[e][c] = sum_d Wk[e][d]*W_h[d][c]) ----------------
__global__ __launch_bounds__(128) void k1_M(const float* __restrict__ Wk,
                                            const float* __restrict__ Wh,
                                            short* __restrict__ Mbf) {
    __shared__ float wk[128];
    const int e = blockIdx.x, c = threadIdx.x;
    wk[c] = Wk[e * 128 + c];
    __syncthreads();
    float s = 0.f;
#pragma unroll 4
    for (int d = 0; d < 128; ++d) s += wk[d] * Wh[d * 128 + c];
    Mbf[e * 128 + c] = f2bf(s);
}

// ---------------- K2: per-b prep ----------------
__global__ __launch_bounds__(128) void k2_prep(
    const int* __restrict__ user_idx, const int* __restrict__ item_idx,
    const int* __restrict__ user_hist, const float* __restrict__ user_embed,
    const float* __restrict__ item_embed, const float* __restrict__ W_i,
    const float* __restrict__ Wq, float* __restrict__ uid_o,
    float* __restrict__ tid_o, float* __restrict__ qu_o, float* __restrict__ qt_o,
    int* __restrict__ hist_o, float* __restrict__ maskf_o) {
    const int b = blockIdx.x, t = threadIdx.x;
    const int ui = user_idx[b], ii = item_idx[b];
    __shared__ float uid_s[128], traw_s[128], tid_s[128];
    const float uv = user_embed[(long)ui * 128 + t];
    const float tv = item_embed[(long)ii * 128 + t];
    uid_s[t] = uv;
    traw_s[t] = tv;
    uid_o[b * 128 + t] = uv;
    for (int l = t; l < L_; l += 128) {
        const int hv = user_hist[(long)ui * L_ + l];
        hist_o[b * L_ + l] = hv;
        maskf_o[b * L_ + l] = (hv != ii && hv != NITEMS) ? 1.f : 0.f;
    }
    __syncthreads();
    float tidv = 0.f, quv = 0.f;
#pragma unroll 2
    for (int c = 0; c < 128; c += 4) {
        const float4 wi = *reinterpret_cast<const float4*>(&W_i[t * 128 + c]);
        const float4 wq = *reinterpret_cast<const float4*>(&Wq[t * 128 + c]);
        tidv += wi.x * traw_s[c] + wi.y * traw_s[c + 1] + wi.z * traw_s[c + 2] + wi.w * traw_s[c + 3];
        quv  += wq.x * uid_s[c]  + wq.y * uid_s[c + 1]  + wq.z * uid_s[c + 2]  + wq.w * uid_s[c + 3];
    }
    tid_s[t] = tidv;
    tid_o[b * 128 + t] = tidv;
    qu_o[b * 128 + t] = quv;
    __syncthreads();
    float qtv = 0.f;
#pragma unroll 2
    for (int c = 0; c < 128; c += 4) {
        const float4 wq = *reinterpret_cast<const float4*>(&Wq[t * 128 + c]);
        qtv += wq.x * tid_s[c] + wq.y * tid_s[c + 1] + wq.z * tid_s[c + 2] + wq.w * tid_s[c + 3];
    }
    qt_o[b * 128 + t] = qtv;
}

// ---------------- K3: MFMA score GEMM + fused epilogue ----------------
// 128 gathered rows per block (4 waves x 2 row-tiles of 16), cols e = 128.
// kw[r][e] = sum_c A[r][c] * M[e][c]  via mfma_f32_16x16x32_bf16,
// then score_{u,i}[r] = sum_e v[e]*tanh(q_{u,t}[b][e] + kw[r][e]) / TAU.
__global__ __launch_bounds__(256) void k3_scores(
    const short* __restrict__ Mbf, const float* __restrict__ item_embed,
    const int* __restrict__ hist_g, const float* __restrict__ qu_,
    const float* __restrict__ qt_, const float* __restrict__ v_attn,
    float* __restrict__ scu, float* __restrict__ sci) {
    // A staged in fragment order: [tile][ks][kgrp][row][8 bf16]
    __shared__ __align__(16) short A_lds[8][4][4][16][8];
    const int t = threadIdx.x;
    const int rbase = blockIdx.x * 128;

    // ---- stage A (gather + fp32->bf16) ----
    {
        const int rt = t >> 1, kh = t & 1;          // row-in-block, k-half
        const int idx = hist_g[rbase + rt];
        const float* src = item_embed + (long)idx * 128 + kh * 64;
        const int tile = rt >> 4, ri = rt & 15;
#pragma unroll
        for (int kk = 0; kk < 2; ++kk) {
            const int ks = kh * 2 + kk;
#pragma unroll
            for (int g = 0; g < 4; ++g) {
                const float4 f0 = *reinterpret_cast<const float4*>(src + kk * 32 + g * 8);
                const float4 f1 = *reinterpret_cast<const float4*>(src + kk * 32 + g * 8 + 4);
                short8v wv;
                wv[0] = f2bf(f0.x); wv[1] = f2bf(f0.y); wv[2] = f2bf(f0.z); wv[3] = f2bf(f0.w);
                wv[4] = f2bf(f1.x); wv[5] = f2bf(f1.y); wv[6] = f2bf(f1.z); wv[7] = f2bf(f1.w);
                *reinterpret_cast<short8v*>(&A_lds[tile][ks][g][ri][0]) = wv;
            }
        }
    }
    __syncthreads();

    const int w = t >> 6, l = t & 63;
    const int lo = l & 15, hi = l >> 4;

    float vv[8];
#pragma unroll
    for (int j = 0; j < 8; ++j) vv[j] = v_attn[j * 16 + lo];

#pragma unroll
    for (int tt = 0; tt < 2; ++tt) {
        const int tileid = w * 2 + tt;
        // A fragments for this 16-row tile
        short8v af[4];
#pragma unroll
        for (int ks = 0; ks < 4; ++ks)
            af[ks] = *reinterpret_cast<const short8v*>(&A_lds[tileid][ks][hi][lo][0]);

        // rows / batch ids for epilogue
        int rr[4], bb[4];
#pragma unroll
        for (int reg = 0; reg < 4; ++reg) {
            rr[reg] = rbase + tileid * 16 + hi * 4 + reg;
            bb[reg] = rr[reg] / L_;
        }

        float su[4] = {0.f, 0.f, 0.f, 0.f};
        float si[4] = {0.f, 0.f, 0.f, 0.f};

#pragma unroll
        for (int half = 0; half < 2; ++half) {
            // B fragments: lane l holds M[e][c0..c0+8), e = etile*16+lo, c0 = ks*32+hi*8
            short8v bf[4][4];
#pragma unroll
            for (int et = 0; et < 4; ++et) {
                const int e = (half * 4 + et) * 16 + lo;
#pragma unroll
                for (int ks = 0; ks < 4; ++ks) {
                    const int c0 = ks * 32 + hi * 8;
                    bf[et][ks] = *reinterpret_cast<const short8v*>(Mbf + e * 128 + c0);
                }
            }
            floatx4 acc[4];
#pragma unroll
            for (int et = 0; et < 4; ++et) acc[et] = (floatx4){0.f, 0.f, 0.f, 0.f};
#pragma unroll
            for (int ks = 0; ks < 4; ++ks)
#pragma unroll
                for (int et = 0; et < 4; ++et)
                    acc[et] = __builtin_amdgcn_mfma_f32_16x16x32_bf16(af[ks], bf[et][ks],
                                                                      acc[et], 0, 0, 0);
            // fused epilogue for this e-half
#pragma unroll
            for (int et = 0; et < 4; ++et) {
                const int j = half * 4 + et;
                const int e = j * 16 + lo;
#pragma unroll
                for (int reg = 0; reg < 4; ++reg) {
                    const float kw = acc[et][reg];
                    su[reg] += vv[j] * fast_tanh(qu_[bb[reg] * 128 + e] + kw);
                    si[reg] += vv[j] * fast_tanh(qt_[bb[reg] * 128 + e] + kw);
                }
            }
        }

        // reduce over the 16 lanes of each row group and write
#pragma unroll
        for (int reg = 0; reg < 4; ++reg) {
            float s0 = su[reg], s1 = si[reg];
#pragma unroll
            for (int m = 1; m < 16; m <<= 1) {
                s0 += __shfl_xor(s0, m, 64);
                s1 += __shfl_xor(s1, m, 64);
            }
            if (lo == 0) {
                scu[rr[reg]] = s0 * 0.25f;  // /TAU
                sci[rr[reg]] = s1 * 0.25f;
            }
        }
    }
}

// ---------------- K4: softmax + lognormal weights + KL partials ----------------
__global__ __launch_bounds__(256) void k4_softmax(
    const float* __restrict__ scu, const float* __restrict__ sci,
    const float* __restrict__ maskf, const float* __restrict__ noise_u,
    const float* __restrict__ noise_i, float* __restrict__ atu,
    float* __restrict__ ati, float* __restrict__ klu, float* __restrict__ kli,
    float* __restrict__ msm) {
    const int b = blockIdx.x, t = threadIdx.x;
    __shared__ float red[4];
    const bool act = t < L_;
    const int off = b * L_ + t;
    const float mk = act ? maskf[off] : 0.f;
    const float msum_v = bsum256(mk, red);
    if (t == 0) msm[b] = msum_v;

    const float* sc[2] = {scu, sci};
    const float* nz[2] = {noise_u, noise_i};
    float* at[2] = {atu, ati};
    float* kl[2] = {klu, kli};
#pragma unroll
    for (int side = 0; side < 2; ++side) {
        const float s = act ? (mk > 0.5f ? sc[side][off] : -1e9f) : -1e30f;
        const float mx = bmax256(s, red);
        const float e = act ? expf(s - mx) : 0.f;
        const float Z = bsum256(e, red);
        const float phi = e / Z;
        const float mu = logf(phi + 1e-8f);
        const float w = act ? expf(mu + 0.1f * nz[side][off]) * mk : 0.f;
        const float Zw = bsum256(w, red);
        if (act) at[side][off] = w / (Zw + 1e-8f);
        const float klel = act ? (2.3025850929940457f + 0.5f * (0.01f + mu * mu) - 0.5f) * mk : 0.f;
        const float kls = bsum256(klel, red);
        if (t == 0) kl[side][b] = kls;
    }
}

// ---------------- K5: attn apply + W_h matvec + LN + logit ----------------
__global__ __launch_bounds__(128) void k5_out(
    const float* __restrict__ atu, const float* __restrict__ ati,
    const int* __restrict__ hist_g, const float* __restrict__ item_embed,
    const float* __restrict__ W_h, const float* __restrict__ uid,
    const float* __restrict__ tid, const float* __restrict__ gamma_u,
    const float* __restrict__ beta_u, const float* __restrict__ gamma_i,
    const float* __restrict__ beta_i, const float* __restrict__ pred_W,
    const float* __restrict__ pred_b, float* __restrict__ out) {
    const int b = blockIdx.x, t = threadIdx.x;
    __shared__ float au[L_], ai[L_];
    __shared__ int hg[L_];
    __shared__ float aru[128], ari[128];
    __shared__ float red[2];
    for (int l = t; l < L_; l += 128) {
        au[l] = atu[b * L_ + l];
        ai[l] = ati[b * L_ + l];
        hg[l] = hist_g[b * L_ + l];
    }
    __syncthreads();
    float su = 0.f, si = 0.f;
#pragma unroll 4
    for (int l = 0; l < L_; ++l) {
        const float h = item_embed[(long)hg[l] * 128 + t];
        su += au[l] * h;
        si += ai[l] * h;
    }
    aru[t] = su;
    ari[t] = si;
    __syncthreads();
    float ou = 0.f, oi = 0.f;
#pragma unroll 2
    for (int c = 0; c < 128; c += 4) {
        const float4 w = *reinterpret_cast<const float4*>(&W_h[t * 128 + c]);
        ou += w.x * aru[c] + w.y * aru[c + 1] + w.z * aru[c + 2] + w.w * aru[c + 3];
        oi += w.x * ari[c] + w.y * ari[c + 1] + w.z * ari[c + 2] + w.w * ari[c + 3];
    }
    const float xu = ou * uid[b * 128 + t];
    const float xi = oi * tid[b * 128 + t];
    const float mu_ = bsum128(xu, red) * (1.f / 128.f);
    const float du = xu - mu_;
    const float vu = bsum128(du * du, red) * (1.f / 128.f);
    const float u = du * rsqrtf(vu + 1e-5f) * gamma_u[t] + beta_u[t];
    const float mi_ = bsum128(xi, red) * (1.f / 128.f);
    const float di = xi - mi_;
    const float vi = bsum128(di * di, red) * (1.f / 128.f);
    const float iv = di * rsqrtf(vi + 1e-5f) * gamma_i[t] + beta_i[t];
    const float p = bsum128(u * iv * pred_W[t], red);
    if (t == 0) out[b] = p + pred_b[0];
}

// ---------------- K6: KL final reduction ----------------
__global__ __launch_bounds__(256) void k6_kl(const float* __restrict__ klu,
                                             const float* __restrict__ kli,
                                             const float* __restrict__ msm,
                                             float* __restrict__ out) {
    __shared__ float red[4];
    const int t = threadIdx.x;
    float su = 0.f, si = 0.f, sm = 0.f;
    for (int b = t; b < B_; b += 256) {
        su += klu[b];
        si += kli[b];
        sm += msm[b];
    }
    su = bsum256(su, red);
    si = bsum256(si, red);
    sm = bsum256(sm, red);
    if (t == 0) {
        const float inv = 1.f / (sm + 1e-8f);
        out[0] = 0.5f * (su * inv + si * inv);
    }
}

extern "C" void kernel_launch(void* const* d_in, const int* in_sizes, int n_in,
                              void* d_out, int out_size, void* d_ws, size_t ws_size,
                              hipStream_t stream) {
    const int* user_idx = (const int*)d_in[0];
    const int* item_idx = (const int*)d_in[1];
    const int* user_hist = (const int*)d_in[2];
    const float* user_embed = (const float*)d_in[3];
    const float* item_embed = (const float*)d_in[4];
    const float* W_i = (const float*)d_in[5];
    const float* W_h = (const float*)d_in[6];
    const float* Wq = (const float*)d_in[7];
    const float* Wk = (const float*)d_in[8];
    const float* v_attn = (const float*)d_in[9];
    const float* pred_W = (const float*)d_in[10];
    const float* pred_b = (const float*)d_in[11];
    const float* gamma_u = (const float*)d_in[12];
    const float* beta_u = (const float*)d_in[13];
    const float* gamma_i = (const float*)d_in[14];
    const float* beta_i = (const float*)d_in[15];
    const float* noise_u = (const float*)d_in[16];
    const float* noise_i = (const float*)d_in[17];
    float* out = (float*)d_out;

    char* ws = (char*)d_ws;
    size_t off = 0;
    auto alloc = [&](size_t bytes) -> void* {
        void* p = ws + off;
        off = (off + bytes + 255) & ~(size_t)255;
        return p;
    };
    short* Mbf = (short*)alloc(128 * 128 * 2);
    float* uid = (float*)alloc((size_t)B_ * 128 * 4);
    float* tid = (float*)alloc((size_t)B_ * 128 * 4);
    float* qu  = (float*)alloc((size_t)B_ * 128 * 4);
    float* qt  = (float*)alloc((size_t)B_ * 128 * 4);
    int* hg    = (int*)alloc((size_t)B_ * L_ * 4);
    float* mkf = (float*)alloc((size_t)B_ * L_ * 4);
    float* scu = (float*)alloc((size_t)B_ * L_ * 4);
    float* sci = (float*)alloc((size_t)B_ * L_ * 4);
    float* atu = (float*)alloc((size_t)B_ * L_ * 4);
    float* ati = (float*)alloc((size_t)B_ * L_ * 4);
    float* klu = (float*)alloc((size_t)B_ * 4);
    float* kli = (float*)alloc((size_t)B_ * 4);
    float* msm = (float*)alloc((size_t)B_ * 4);

    k1_M<<<128, 128, 0, stream>>>(Wk, W_h, Mbf);
    k2_prep<<<B_, 128, 0, stream>>>(user_idx, item_idx, user_hist, user_embed,
                                    item_embed, W_i, Wq, uid, tid, qu, qt, hg, mkf);
    k3_scores<<<(B_ * L_) / 128, 256, 0, stream>>>(Mbf, item_embed, hg, qu, qt, v_attn,
                                                   scu, sci);
    k4_softmax<<<B_, 256, 0, stream>>>(scu, sci, mkf, noise_u, noise_i, atu, ati,
                                       klu, kli, msm);
    k5_out<<<B_, 128, 0, stream>>>(atu, ati, hg, item_embed, W_h, uid, tid, gamma_u,
                                   beta_u, gamma_i, beta_i, pred_W, pred_b, out);
    k6_kl<<<1, 256, 0, stream>>>(klu, kli, msm, out + B_);
}

// Round 3
// 235.044 us; speedup vs baseline: 3.5384x; 1.0653x over previous
//
#include <hip/hip_runtime.h>

#define B_ 2048
#define L_ 200
#define D_ 128
#define NITEMS 50000

typedef __attribute__((ext_vector_type(8))) short short8v;
typedef __attribute__((ext_vector_type(4))) float floatx4;

// ---------------- helpers ----------------
__device__ __forceinline__ short f2bf(float f) {
    union { float f; unsigned u; } v;
    v.f = f;
    unsigned r = v.u + 0x7FFFu + ((v.u >> 16) & 1u);
    return (short)(r >> 16);
}
__device__ __forceinline__ float bf2f(short s) {
    union { unsigned u; float f; } v;
    v.u = ((unsigned)(unsigned short)s) << 16;
    return v.f;
}

__device__ __forceinline__ float fast_tanh(float x) {
    x = fminf(fmaxf(x, -15.f), 15.f);
    const float t = exp2f(x * 2.885390081777927f);  // e^(2x)
    return (t - 1.f) * __builtin_amdgcn_rcpf(t + 1.f);
}

__device__ __forceinline__ float wave_sum(float v) {
#pragma unroll
    for (int m = 32; m >= 1; m >>= 1) v += __shfl_xor(v, m, 64);
    return v;
}
__device__ __forceinline__ float wave_max(float v) {
#pragma unroll
    for (int m = 32; m >= 1; m >>= 1) v = fmaxf(v, __shfl_xor(v, m, 64));
    return v;
}
__device__ __forceinline__ float bsum128(float v, float* red) {
    v = wave_sum(v);
    __syncthreads();
    if ((threadIdx.x & 63) == 0) red[threadIdx.x >> 6] = v;
    __syncthreads();
    return red[0] + red[1];
}

// ---------------- K0: item_embed -> bf16 table ----------------
__global__ __launch_bounds__(256) void k0_cvt(const float* __restrict__ src,
                                              short* __restrict__ dst, int n8) {
    const int i = blockIdx.x * 256 + threadIdx.x;
    if (i >= n8) return;
    const float4 f0 = *reinterpret_cast<const float4*>(src + i * 8);
    const float4 f1 = *reinterpret_cast<const float4*>(src + i * 8 + 4);
    short8v w;
    w[0] = f2bf(f0.x); w[1] = f2bf(f0.y); w[2] = f2bf(f0.z); w[3] = f2bf(f0.w);
    w[4] = f2bf(f1.x); w[5] = f2bf(f1.y); w[6] = f2bf(f1.z); w[7] = f2bf(f1.w);
    *reinterpret_cast<short8v*>(dst + i * 8) = w;
}

// ---------------- K1: Mbf = bf16( Wk @ W_h ) ----------------
__global__ __launch_bounds__(128) void k1_M(const float* __restrict__ Wk,
                                            const float* __restrict__ Wh,
                                            short* __restrict__ Mbf) {
    __shared__ float wk[128];
    const int e = blockIdx.x, c = threadIdx.x;
    wk[c] = Wk[e * 128 + c];
    __syncthreads();
    float s = 0.f;
#pragma unroll 4
    for (int d = 0; d < 128; ++d) s += wk[d] * Wh[d * 128 + c];
    Mbf[e * 128 + c] = f2bf(s);
}

// ---------------- K2: per-b prep ----------------
__global__ __launch_bounds__(128) void k2_prep(
    const int* __restrict__ user_idx, const int* __restrict__ item_idx,
    const int* __restrict__ user_hist, const float* __restrict__ user_embed,
    const float* __restrict__ item_embed, const float* __restrict__ W_i,
    const float* __restrict__ Wq, float* __restrict__ uid_o,
    float* __restrict__ tid_o, float* __restrict__ qu_o, float* __restrict__ qt_o,
    int* __restrict__ hist_o, float* __restrict__ maskf_o) {
    const int b = blockIdx.x, t = threadIdx.x;
    const int ui = user_idx[b], ii = item_idx[b];
    __shared__ float uid_s[128], traw_s[128], tid_s[128];
    const float uv = user_embed[(long)ui * 128 + t];
    const float tv = item_embed[(long)ii * 128 + t];
    uid_s[t] = uv;
    traw_s[t] = tv;
    uid_o[b * 128 + t] = uv;
    for (int l = t; l < L_; l += 128) {
        const int hv = user_hist[(long)ui * L_ + l];
        hist_o[b * L_ + l] = hv;
        maskf_o[b * L_ + l] = (hv != ii && hv != NITEMS) ? 1.f : 0.f;
    }
    __syncthreads();
    float tidv = 0.f, quv = 0.f;
#pragma unroll 2
    for (int c = 0; c < 128; c += 4) {
        const float4 wi = *reinterpret_cast<const float4*>(&W_i[t * 128 + c]);
        const float4 wq = *reinterpret_cast<const float4*>(&Wq[t * 128 + c]);
        tidv += wi.x * traw_s[c] + wi.y * traw_s[c + 1] + wi.z * traw_s[c + 2] + wi.w * traw_s[c + 3];
        quv  += wq.x * uid_s[c]  + wq.y * uid_s[c + 1]  + wq.z * uid_s[c + 2]  + wq.w * uid_s[c + 3];
    }
    tid_s[t] = tidv;
    tid_o[b * 128 + t] = tidv;
    qu_o[b * 128 + t] = quv;
    __syncthreads();
    float qtv = 0.f;
#pragma unroll 2
    for (int c = 0; c < 128; c += 4) {
        const float4 wq = *reinterpret_cast<const float4*>(&Wq[t * 128 + c]);
        qtv += wq.x * tid_s[c] + wq.y * tid_s[c + 1] + wq.z * tid_s[c + 2] + wq.w * tid_s[c + 3];
    }
    qt_o[b * 128 + t] = qtv;
}

// ---------------- K3: MFMA score GEMM + fused epilogue ----------------
__global__ __launch_bounds__(256) void k3_scores(
    const short* __restrict__ Mbf, const short* __restrict__ item_bf,
    const int* __restrict__ hist_g, const float* __restrict__ qu_,
    const float* __restrict__ qt_, const float* __restrict__ v_attn,
    float* __restrict__ scu, float* __restrict__ sci) {
    __shared__ __align__(16) short A_lds[8][4][4][16][8];
    __shared__ float qu_s[2][128], qt_s[2][128];
    const int t = threadIdx.x;
    const int rbase = blockIdx.x * 128;
    const int b0 = rbase / L_;

    // stage the <=2 q rows this block touches
    {
        const int row = t >> 7, e = t & 127;
        const int bc = min(b0 + row, B_ - 1);
        qu_s[row][e] = qu_[bc * 128 + e];
        qt_s[row][e] = qt_[bc * 128 + e];
    }
    // stage A (bf16 gather, fragment order)
    {
        const int rt = t >> 1, kh = t & 1;
        const int idx = hist_g[rbase + rt];
        const short* src = item_bf + (long)idx * 128 + kh * 64;
        const int tile = rt >> 4, ri = rt & 15;
#pragma unroll
        for (int kk = 0; kk < 2; ++kk)
#pragma unroll
            for (int g = 0; g < 4; ++g)
                *reinterpret_cast<short8v*>(&A_lds[tile][kh * 2 + kk][g][ri][0]) =
                    *reinterpret_cast<const short8v*>(src + kk * 32 + g * 8);
    }
    __syncthreads();

    const int w = t >> 6, l = t & 63;
    const int lo = l & 15, hi = l >> 4;

    float vv[8];
#pragma unroll
    for (int j = 0; j < 8; ++j) vv[j] = v_attn[j * 16 + lo];

#pragma unroll
    for (int tt = 0; tt < 2; ++tt) {
        const int tileid = w * 2 + tt;
        short8v af[4];
#pragma unroll
        for (int ks = 0; ks < 4; ++ks)
            af[ks] = *reinterpret_cast<const short8v*>(&A_lds[tileid][ks][hi][lo][0]);

        int rr[4], bs[4];
#pragma unroll
        for (int reg = 0; reg < 4; ++reg) {
            rr[reg] = rbase + tileid * 16 + hi * 4 + reg;
            bs[reg] = rr[reg] / L_ - b0;
        }

        float su[4] = {0.f, 0.f, 0.f, 0.f};
        float si[4] = {0.f, 0.f, 0.f, 0.f};

#pragma unroll
        for (int half = 0; half < 2; ++half) {
            short8v bf[4][4];
#pragma unroll
            for (int et = 0; et < 4; ++et) {
                const int e = (half * 4 + et) * 16 + lo;
#pragma unroll
                for (int ks = 0; ks < 4; ++ks)
                    bf[et][ks] = *reinterpret_cast<const short8v*>(Mbf + e * 128 + ks * 32 + hi * 8);
            }
            floatx4 acc[4];
#pragma unroll
            for (int et = 0; et < 4; ++et) acc[et] = (floatx4){0.f, 0.f, 0.f, 0.f};
#pragma unroll
            for (int ks = 0; ks < 4; ++ks)
#pragma unroll
                for (int et = 0; et < 4; ++et)
                    acc[et] = __builtin_amdgcn_mfma_f32_16x16x32_bf16(af[ks], bf[et][ks],
                                                                      acc[et], 0, 0, 0);
#pragma unroll
            for (int et = 0; et < 4; ++et) {
                const int j = half * 4 + et;
                const int e = j * 16 + lo;
#pragma unroll
                for (int reg = 0; reg < 4; ++reg) {
                    const float kw = acc[et][reg];
                    su[reg] += vv[j] * fast_tanh(qu_s[bs[reg]][e] + kw);
                    si[reg] += vv[j] * fast_tanh(qt_s[bs[reg]][e] + kw);
                }
            }
        }

#pragma unroll
        for (int reg = 0; reg < 4; ++reg) {
            float s0 = su[reg], s1 = si[reg];
#pragma unroll
            for (int m = 1; m < 16; m <<= 1) {
                s0 += __shfl_xor(s0, m, 64);
                s1 += __shfl_xor(s1, m, 64);
            }
            if (lo == 0) {
                scu[rr[reg]] = s0 * 0.25f;
                sci[rr[reg]] = s1 * 0.25f;
            }
        }
    }
}

// ---------------- K4: wave-per-b softmax + lognormal weights + KL partials ----------------
__global__ __launch_bounds__(256) void k4_softmax(
    const float* __restrict__ scu, const float* __restrict__ sci,
    const float* __restrict__ maskf, const float* __restrict__ noise_u,
    const float* __restrict__ noise_i, float* __restrict__ atu,
    float* __restrict__ ati, float* __restrict__ klu, float* __restrict__ kli,
    float* __restrict__ msm) {
    const int wv = threadIdx.x >> 6, lane = threadIdx.x & 63;
    const int b = blockIdx.x * 4 + wv;
    const int base = b * L_;

    float mk[4];
    float msl = 0.f;
#pragma unroll
    for (int k = 0; k < 4; ++k) {
        const int l = lane + 64 * k;
        mk[k] = (l < L_) ? maskf[base + l] : 0.f;
        msl += mk[k];
    }
    const float msum_v = wave_sum(msl);
    if (lane == 0) msm[b] = msum_v;

    const float* sc[2] = {scu, sci};
    const float* nz[2] = {noise_u, noise_i};
    float* at[2] = {atu, ati};
    float* kl[2] = {klu, kli};
#pragma unroll
    for (int side = 0; side < 2; ++side) {
        float s[4];
        float mloc = -1e30f;
#pragma unroll
        for (int k = 0; k < 4; ++k) {
            const int l = lane + 64 * k;
            s[k] = (l < L_) ? (mk[k] > 0.5f ? sc[side][base + l] : -1e9f) : -1e30f;
            mloc = fmaxf(mloc, s[k]);
        }
        const float mx = wave_max(mloc);
        float e[4], esum = 0.f;
#pragma unroll
        for (int k = 0; k < 4; ++k) {
            const int l = lane + 64 * k;
            e[k] = (l < L_) ? expf(s[k] - mx) : 0.f;
            esum += e[k];
        }
        const float Z = wave_sum(esum);
        const float invZ = 1.f / Z;
        float w[4], mu[4], wsum = 0.f, klsum = 0.f;
#pragma unroll
        for (int k = 0; k < 4; ++k) {
            const int l = lane + 64 * k;
            const float phi = e[k] * invZ;
            mu[k] = logf(phi + 1e-8f);
            w[k] = (l < L_) ? expf(mu[k] + 0.1f * nz[side][base + l]) * mk[k] : 0.f;
            wsum += w[k];
            klsum += (l < L_) ? (2.3025850929940457f + 0.5f * (0.01f + mu[k] * mu[k]) - 0.5f) * mk[k] : 0.f;
        }
        const float Zw = wave_sum(wsum);
        const float invZw = 1.f / (Zw + 1e-8f);
#pragma unroll
        for (int k = 0; k < 4; ++k) {
            const int l = lane + 64 * k;
            if (l < L_) at[side][base + l] = w[k] * invZw;
        }
        const float kls = wave_sum(klsum);
        if (lane == 0) kl[side][b] = kls;
    }
}

// ---------------- K5: attn apply (bf16 V) + W_h matvec + LN + logit ----------------
__global__ __launch_bounds__(128) void k5_out(
    const float* __restrict__ atu, const float* __restrict__ ati,
    const int* __restrict__ hist_g, const short* __restrict__ item_bf,
    const float* __restrict__ W_h, const float* __restrict__ uid,
    const float* __restrict__ tid, const float* __restrict__ gamma_u,
    const float* __restrict__ beta_u, const float* __restrict__ gamma_i,
    const float* __restrict__ beta_i, const float* __restrict__ pred_W,
    const float* __restrict__ pred_b, float* __restrict__ out) {
    const int b = blockIdx.x, t = threadIdx.x;
    __shared__ float au[L_], ai[L_];
    __shared__ int hg[L_];
    __shared__ float aru[128], ari[128];
    __shared__ float red[2];
    for (int l = t; l < L_; l += 128) {
        au[l] = atu[b * L_ + l];
        ai[l] = ati[b * L_ + l];
        hg[l] = hist_g[b * L_ + l];
    }
    __syncthreads();
    float su = 0.f, si = 0.f;
#pragma unroll 4
    for (int l = 0; l < L_; ++l) {
        const float h = bf2f(item_bf[(long)hg[l] * 128 + t]);
        su += au[l] * h;
        si += ai[l] * h;
    }
    aru[t] = su;
    ari[t] = si;
    __syncthreads();
    float ou = 0.f, oi = 0.f;
#pragma unroll 2
    for (int c = 0; c < 128; c += 4) {
        const float4 w = *reinterpret_cast<const float4*>(&W_h[t * 128 + c]);
        ou += w.x * aru[c] + w.y * aru[c + 1] + w.z * aru[c + 2] + w.w * aru[c + 3];
        oi += w.x * ari[c] + w.y * ari[c + 1] + w.z * ari[c + 2] + w.w * ari[c + 3];
    }
    const float xu = ou * uid[b * 128 + t];
    const float xi = oi * tid[b * 128 + t];
    const float mu_ = bsum128(xu, red) * (1.f / 128.f);
    const float du = xu - mu_;
    const float vu = bsum128(du * du, red) * (1.f / 128.f);
    const float u = du * rsqrtf(vu + 1e-5f) * gamma_u[t] + beta_u[t];
    const float mi_ = bsum128(xi, red) * (1.f / 128.f);
    const float di = xi - mi_;
    const float vi = bsum128(di * di, red) * (1.f / 128.f);
    const float iv = di * rsqrtf(vi + 1e-5f) * gamma_i[t] + beta_i[t];
    const float p = bsum128(u * iv * pred_W[t], red);
    if (t == 0) out[b] = p + pred_b[0];
}

// ---------------- K6: KL final reduction ----------------
__global__ __launch_bounds__(256) void k6_kl(const float* __restrict__ klu,
                                             const float* __restrict__ kli,
                                             const float* __restrict__ msm,
                                             float* __restrict__ out) {
    __shared__ float red[4];
    const int t = threadIdx.x;
    float su = 0.f, si = 0.f, sm = 0.f;
    for (int b = t; b < B_; b += 256) {
        su += klu[b];
        si += kli[b];
        sm += msm[b];
    }
    su = wave_sum(su);
    si = wave_sum(si);
    sm = wave_sum(sm);
    __syncthreads();
    if ((t & 63) == 0) red[t >> 6] = su;
    __syncthreads();
    su = red[0] + red[1] + red[2] + red[3];
    __syncthreads();
    if ((t & 63) == 0) red[t >> 6] = si;
    __syncthreads();
    si = red[0] + red[1] + red[2] + red[3];
    __syncthreads();
    if ((t & 63) == 0) red[t >> 6] = sm;
    __syncthreads();
    sm = red[0] + red[1] + red[2] + red[3];
    if (t == 0) {
        const float inv = 1.f / (sm + 1e-8f);
        out[0] = 0.5f * (su * inv + si * inv);
    }
}

extern "C" void kernel_launch(void* const* d_in, const int* in_sizes, int n_in,
                              void* d_out, int out_size, void* d_ws, size_t ws_size,
                              hipStream_t stream) {
    const int* user_idx = (const int*)d_in[0];
    const int* item_idx = (const int*)d_in[1];
    const int* user_hist = (const int*)d_in[2];
    const float* user_embed = (const float*)d_in[3];
    const float* item_embed = (const float*)d_in[4];
    const float* W_i = (const float*)d_in[5];
    const float* W_h = (const float*)d_in[6];
    const float* Wq = (const float*)d_in[7];
    const float* Wk = (const float*)d_in[8];
    const float* v_attn = (const float*)d_in[9];
    const float* pred_W = (const float*)d_in[10];
    const float* pred_b = (const float*)d_in[11];
    const float* gamma_u = (const float*)d_in[12];
    const float* beta_u = (const float*)d_in[13];
    const float* gamma_i = (const float*)d_in[14];
    const float* beta_i = (const float*)d_in[15];
    const float* noise_u = (const float*)d_in[16];
    const float* noise_i = (const float*)d_in[17];
    float* out = (float*)d_out;

    char* ws = (char*)d_ws;
    size_t off = 0;
    auto alloc = [&](size_t bytes) -> void* {
        void* p = ws + off;
        off = (off + bytes + 255) & ~(size_t)255;
        return p;
    };
    short* Mbf    = (short*)alloc(128 * 128 * 2);
    short* item_bf = (short*)alloc((size_t)(NITEMS + 1) * 128 * 2);
    float* uid = (float*)alloc((size_t)B_ * 128 * 4);
    float* tid = (float*)alloc((size_t)B_ * 128 * 4);
    float* qu  = (float*)alloc((size_t)B_ * 128 * 4);
    float* qt  = (float*)alloc((size_t)B_ * 128 * 4);
    int* hg    = (int*)alloc((size_t)B_ * L_ * 4);
    float* mkf = (float*)alloc((size_t)B_ * L_ * 4);
    float* scu = (float*)alloc((size_t)B_ * L_ * 4);
    float* sci = (float*)alloc((size_t)B_ * L_ * 4);
    float* atu = (float*)alloc((size_t)B_ * L_ * 4);
    float* ati = (float*)alloc((size_t)B_ * L_ * 4);
    float* klu = (float*)alloc((size_t)B_ * 4);
    float* kli = (float*)alloc((size_t)B_ * 4);
    float* msm = (float*)alloc((size_t)B_ * 4);

    const int n8 = (NITEMS + 1) * 128 / 8;
    k0_cvt<<<(n8 + 255) / 256, 256, 0, stream>>>(item_embed, item_bf, n8);
    k1_M<<<128, 128, 0, stream>>>(Wk, W_h, Mbf);
    k2_prep<<<B_, 128, 0, stream>>>(user_idx, item_idx, user_hist, user_embed,
                                    item_embed, W_i, Wq, uid, tid, qu, qt, hg, mkf);
    k3_scores<<<(B_ * L_) / 128, 256, 0, stream>>>(Mbf, item_bf, hg, qu, qt, v_attn,
                                                   scu, sci);
    k4_softmax<<<B_ / 4, 256, 0, stream>>>(scu, sci, mkf, noise_u, noise_i, atu, ati,
                                           klu, kli, msm);
    k5_out<<<B_, 128, 0, stream>>>(atu, ati, hg, item_bf, W_h, uid, tid, gamma_u,
                                   beta_u, gamma_i, beta_i, pred_W, pred_b, out);
    k6_kl<<<1, 256, 0, stream>>>(klu, kli, msm, out + B_);
}

// Round 4
// 230.934 us; speedup vs baseline: 3.6013x; 1.0178x over previous
//
#include <hip/hip_runtime.h>

#define B_ 2048
#define L_ 200
#define D_ 128
#define NITEMS 50000

typedef __attribute__((ext_vector_type(8))) short short8v;
typedef __attribute__((ext_vector_type(4))) float floatx4;

// ---------------- helpers ----------------
__device__ __forceinline__ short f2bf(float f) {
    union { float f; unsigned u; } v;
    v.f = f;
    unsigned r = v.u + 0x7FFFu + ((v.u >> 16) & 1u);
    return (short)(r >> 16);
}
__device__ __forceinline__ float bf2f(short s) {
    union { unsigned u; float f; } v;
    v.u = ((unsigned)(unsigned short)s) << 16;
    return v.f;
}

__device__ __forceinline__ float fast_tanh(float x) {
    x = fminf(fmaxf(x, -15.f), 15.f);
    const float t = exp2f(x * 2.885390081777927f);  // e^(2x)
    return (t - 1.f) * __builtin_amdgcn_rcpf(t + 1.f);
}

__device__ __forceinline__ float wave_sum(float v) {
#pragma unroll
    for (int m = 32; m >= 1; m >>= 1) v += __shfl_xor(v, m, 64);
    return v;
}
__device__ __forceinline__ float wave_max(float v) {
#pragma unroll
    for (int m = 32; m >= 1; m >>= 1) v = fmaxf(v, __shfl_xor(v, m, 64));
    return v;
}
__device__ __forceinline__ float bsum128(float v, float* red) {
    v = wave_sum(v);
    __syncthreads();
    if ((threadIdx.x & 63) == 0) red[threadIdx.x >> 6] = v;
    __syncthreads();
    return red[0] + red[1];
}

// ---------------- K0: item_embed -> bf16 table ----------------
__global__ __launch_bounds__(256) void k0_cvt(const float* __restrict__ src,
                                              short* __restrict__ dst, int n8) {
    const int i = blockIdx.x * 256 + threadIdx.x;
    if (i >= n8) return;
    const float4 f0 = *reinterpret_cast<const float4*>(src + i * 8);
    const float4 f1 = *reinterpret_cast<const float4*>(src + i * 8 + 4);
    short8v w;
    w[0] = f2bf(f0.x); w[1] = f2bf(f0.y); w[2] = f2bf(f0.z); w[3] = f2bf(f0.w);
    w[4] = f2bf(f1.x); w[5] = f2bf(f1.y); w[6] = f2bf(f1.z); w[7] = f2bf(f1.w);
    *reinterpret_cast<short8v*>(dst + i * 8) = w;
}

// ---------------- K1: Mbf = bf16( Wk @ W_h ) ----------------
__global__ __launch_bounds__(128) void k1_M(const float* __restrict__ Wk,
                                            const float* __restrict__ Wh,
                                            short* __restrict__ Mbf) {
    __shared__ float wk[128];
    const int e = blockIdx.x, c = threadIdx.x;
    wk[c] = Wk[e * 128 + c];
    __syncthreads();
    float s = 0.f;
#pragma unroll 4
    for (int d = 0; d < 128; ++d) s += wk[d] * Wh[d * 128 + c];
    Mbf[e * 128 + c] = f2bf(s);
}

// ---------------- K2: per-b prep ----------------
__global__ __launch_bounds__(128) void k2_prep(
    const int* __restrict__ user_idx, const int* __restrict__ item_idx,
    const int* __restrict__ user_hist, const float* __restrict__ user_embed,
    const float* __restrict__ item_embed, const float* __restrict__ W_i,
    const float* __restrict__ Wq, float* __restrict__ uid_o,
    float* __restrict__ tid_o, float* __restrict__ qu_o, float* __restrict__ qt_o,
    int* __restrict__ hist_o, float* __restrict__ maskf_o) {
    const int b = blockIdx.x, t = threadIdx.x;
    const int ui = user_idx[b], ii = item_idx[b];
    __shared__ float uid_s[128], traw_s[128], tid_s[128];
    const float uv = user_embed[(long)ui * 128 + t];
    const float tv = item_embed[(long)ii * 128 + t];
    uid_s[t] = uv;
    traw_s[t] = tv;
    uid_o[b * 128 + t] = uv;
    for (int l = t; l < L_; l += 128) {
        const int hv = user_hist[(long)ui * L_ + l];
        hist_o[b * L_ + l] = hv;
        maskf_o[b * L_ + l] = (hv != ii && hv != NITEMS) ? 1.f : 0.f;
    }
    __syncthreads();
    float tidv = 0.f, quv = 0.f;
#pragma unroll 2
    for (int c = 0; c < 128; c += 4) {
        const float4 wi = *reinterpret_cast<const float4*>(&W_i[t * 128 + c]);
        const float4 wq = *reinterpret_cast<const float4*>(&Wq[t * 128 + c]);
        tidv += wi.x * traw_s[c] + wi.y * traw_s[c + 1] + wi.z * traw_s[c + 2] + wi.w * traw_s[c + 3];
        quv  += wq.x * uid_s[c]  + wq.y * uid_s[c + 1]  + wq.z * uid_s[c + 2]  + wq.w * uid_s[c + 3];
    }
    tid_s[t] = tidv;
    tid_o[b * 128 + t] = tidv;
    qu_o[b * 128 + t] = quv;
    __syncthreads();
    float qtv = 0.f;
#pragma unroll 2
    for (int c = 0; c < 128; c += 4) {
        const float4 wq = *reinterpret_cast<const float4*>(&Wq[t * 128 + c]);
        qtv += wq.x * tid_s[c] + wq.y * tid_s[c + 1] + wq.z * tid_s[c + 2] + wq.w * tid_s[c + 3];
    }
    qt_o[b * 128 + t] = qtv;
}

// ---------------- K3: transposed MFMA score GEMM + fused epilogue ----------------
// D-rows = e (from M), D-cols = r (gathered history rows).
// Lane (lo=l&15, hi=l>>4) after the k-loop holds kw[e = t8*16+hi*4+reg][r = lo].
// e-sum reduce = 2 shuffle steps across the 4 hi groups.
__global__ __launch_bounds__(256) void k3_scores(
    const short* __restrict__ Mbf, const short* __restrict__ item_bf,
    const int* __restrict__ hist_g, const float* __restrict__ qu_,
    const float* __restrict__ qt_, const float* __restrict__ v_attn,
    float* __restrict__ scu, float* __restrict__ sci) {
    __shared__ __align__(16) short A_lds[8][4][4][16][8];  // [rtile][ks][kgrp][row][8]
    __shared__ float q_lds[2][2][128];                     // [qu/qt][bs][e]
    const int t = threadIdx.x;
    const int rbase = blockIdx.x * 128;
    const int b0 = rbase / L_;

    // stage q rows (<=2 batches per block)
    {
#pragma unroll
        for (int s2 = 0; s2 < 2; ++s2) {
            const int idx = s2 * 256 + t;     // 0..511
            const int side = idx >> 8;        // 0=qu, 1=qt
            const int bs = (idx >> 7) & 1;
            const int e = idx & 127;
            const int bc = min(b0 + bs, B_ - 1);
            q_lds[side][bs][e] = side ? qt_[bc * 128 + e] : qu_[bc * 128 + e];
        }
    }
    // stage gathered rows (B-fragment order)
    {
        const int rt = t >> 1, kh = t & 1;
        const int idx = hist_g[rbase + rt];
        const short* src = item_bf + (long)idx * 128 + kh * 64;
        const int tile = rt >> 4, ri = rt & 15;
#pragma unroll
        for (int kk = 0; kk < 2; ++kk)
#pragma unroll
            for (int g = 0; g < 4; ++g)
                *reinterpret_cast<short8v*>(&A_lds[tile][kh * 2 + kk][g][ri][0]) =
                    *reinterpret_cast<const short8v*>(src + kk * 32 + g * 8);
    }
    __syncthreads();

    const int w = t >> 6, l = t & 63;
    const int lo = l & 15, hi = l >> 4;

    // preload v_attn in epilogue (D-row) layout: v4[t8][reg] = v[t8*16 + hi*4 + reg]
    floatx4 v4[8];
#pragma unroll
    for (int t8 = 0; t8 < 8; ++t8)
        v4[t8] = *reinterpret_cast<const floatx4*>(v_attn + t8 * 16 + hi * 4);

#pragma unroll
    for (int pass = 0; pass < 2; ++pass) {
        const int rt = w * 2 + pass;
        floatx4 acc[8];
#pragma unroll
        for (int t8 = 0; t8 < 8; ++t8) acc[t8] = (floatx4){0.f, 0.f, 0.f, 0.f};

#pragma unroll
        for (int ks = 0; ks < 4; ++ks) {
            const short8v bfrag = *reinterpret_cast<const short8v*>(&A_lds[rt][ks][hi][lo][0]);
            short8v mf[8];
#pragma unroll
            for (int t8 = 0; t8 < 8; ++t8)
                mf[t8] = *reinterpret_cast<const short8v*>(Mbf + (t8 * 16 + lo) * 128 + ks * 32 + hi * 8);
#pragma unroll
            for (int t8 = 0; t8 < 8; ++t8)
                acc[t8] = __builtin_amdgcn_mfma_f32_16x16x32_bf16(mf[t8], bfrag, acc[t8], 0, 0, 0);
        }

        // epilogue: lane owns row r = rbase + rt*16 + lo, e's = t8*16 + hi*4 + reg
        const int r = rbase + rt * 16 + lo;
        const int bs = (r >= (b0 + 1) * L_) ? 1 : 0;
        float su = 0.f, si = 0.f;
#pragma unroll
        for (int t8 = 0; t8 < 8; ++t8) {
            const floatx4 qu4 = *reinterpret_cast<const floatx4*>(&q_lds[0][bs][t8 * 16 + hi * 4]);
            const floatx4 qt4 = *reinterpret_cast<const floatx4*>(&q_lds[1][bs][t8 * 16 + hi * 4]);
#pragma unroll
            for (int reg = 0; reg < 4; ++reg) {
                const float kw = acc[t8][reg];
                su += v4[t8][reg] * fast_tanh(qu4[reg] + kw);
                si += v4[t8][reg] * fast_tanh(qt4[reg] + kw);
            }
        }
        su += __shfl_xor(su, 16, 64);
        su += __shfl_xor(su, 32, 64);
        si += __shfl_xor(si, 16, 64);
        si += __shfl_xor(si, 32, 64);
        if (hi == 0) {
            scu[r] = su * 0.25f;  // /TAU
            sci[r] = si * 0.25f;
        }
    }
}

// ---------------- K4: wave-per-b softmax + lognormal weights + KL partials ----------------
__global__ __launch_bounds__(256) void k4_softmax(
    const float* __restrict__ scu, const float* __restrict__ sci,
    const float* __restrict__ maskf, const float* __restrict__ noise_u,
    const float* __restrict__ noise_i, float* __restrict__ atu,
    float* __restrict__ ati, float* __restrict__ klu, float* __restrict__ kli,
    float* __restrict__ msm) {
    const int wv = threadIdx.x >> 6, lane = threadIdx.x & 63;
    const int b = blockIdx.x * 4 + wv;
    const int base = b * L_;

    float mk[4];
    float msl = 0.f;
#pragma unroll
    for (int k = 0; k < 4; ++k) {
        const int l = lane + 64 * k;
        mk[k] = (l < L_) ? maskf[base + l] : 0.f;
        msl += mk[k];
    }
    const float msum_v = wave_sum(msl);
    if (lane == 0) msm[b] = msum_v;

    const float* sc[2] = {scu, sci};
    const float* nz[2] = {noise_u, noise_i};
    float* at[2] = {atu, ati};
    float* kl[2] = {klu, kli};
#pragma unroll
    for (int side = 0; side < 2; ++side) {
        float s[4];
        float mloc = -1e30f;
#pragma unroll
        for (int k = 0; k < 4; ++k) {
            const int l = lane + 64 * k;
            s[k] = (l < L_) ? (mk[k] > 0.5f ? sc[side][base + l] : -1e9f) : -1e30f;
            mloc = fmaxf(mloc, s[k]);
        }
        const float mx = wave_max(mloc);
        float e[4], esum = 0.f;
#pragma unroll
        for (int k = 0; k < 4; ++k) {
            const int l = lane + 64 * k;
            e[k] = (l < L_) ? expf(s[k] - mx) : 0.f;
            esum += e[k];
        }
        const float Z = wave_sum(esum);
        const float invZ = 1.f / Z;
        float w[4], mu[4], wsum = 0.f, klsum = 0.f;
#pragma unroll
        for (int k = 0; k < 4; ++k) {
            const int l = lane + 64 * k;
            const float phi = e[k] * invZ;
            mu[k] = logf(phi + 1e-8f);
            w[k] = (l < L_) ? expf(mu[k] + 0.1f * nz[side][base + l]) * mk[k] : 0.f;
            wsum += w[k];
            klsum += (l < L_) ? (2.3025850929940457f + 0.5f * (0.01f + mu[k] * mu[k]) - 0.5f) * mk[k] : 0.f;
        }
        const float Zw = wave_sum(wsum);
        const float invZw = 1.f / (Zw + 1e-8f);
#pragma unroll
        for (int k = 0; k < 4; ++k) {
            const int l = lane + 64 * k;
            if (l < L_) at[side][base + l] = w[k] * invZw;
        }
        const float kls = wave_sum(klsum);
        if (lane == 0) kl[side][b] = kls;
    }
}

// ---------------- K5: attn apply (bf16 V) + W_h matvec + LN + logit ----------------
__global__ __launch_bounds__(128) void k5_out(
    const float* __restrict__ atu, const float* __restrict__ ati,
    const int* __restrict__ hist_g, const short* __restrict__ item_bf,
    const float* __restrict__ W_h, const float* __restrict__ uid,
    const float* __restrict__ tid, const float* __restrict__ gamma_u,
    const float* __restrict__ beta_u, const float* __restrict__ gamma_i,
    const float* __restrict__ beta_i, const float* __restrict__ pred_W,
    const float* __restrict__ pred_b, float* __restrict__ out) {
    const int b = blockIdx.x, t = threadIdx.x;
    __shared__ float au[L_], ai[L_];
    __shared__ int hg[L_];
    __shared__ float aru[128], ari[128];
    __shared__ float red[2];
    for (int l = t; l < L_; l += 128) {
        au[l] = atu[b * L_ + l];
        ai[l] = ati[b * L_ + l];
        hg[l] = hist_g[b * L_ + l];
    }
    __syncthreads();
    float su = 0.f, si = 0.f;
#pragma unroll 8
    for (int l = 0; l < L_; ++l) {
        const float h = bf2f(item_bf[(long)hg[l] * 128 + t]);
        su += au[l] * h;
        si += ai[l] * h;
    }
    aru[t] = su;
    ari[t] = si;
    __syncthreads();
    float ou = 0.f, oi = 0.f;
#pragma unroll 2
    for (int c = 0; c < 128; c += 4) {
        const float4 w = *reinterpret_cast<const float4*>(&W_h[t * 128 + c]);
        ou += w.x * aru[c] + w.y * aru[c + 1] + w.z * aru[c + 2] + w.w * aru[c + 3];
        oi += w.x * ari[c] + w.y * ari[c + 1] + w.z * ari[c + 2] + w.w * ari[c + 3];
    }
    const float xu = ou * uid[b * 128 + t];
    const float xi = oi * tid[b * 128 + t];
    const float mu_ = bsum128(xu, red) * (1.f / 128.f);
    const float du = xu - mu_;
    const float vu = bsum128(du * du, red) * (1.f / 128.f);
    const float u = du * rsqrtf(vu + 1e-5f) * gamma_u[t] + beta_u[t];
    const float mi_ = bsum128(xi, red) * (1.f / 128.f);
    const float di = xi - mi_;
    const float vi = bsum128(di * di, red) * (1.f / 128.f);
    const float iv = di * rsqrtf(vi + 1e-5f) * gamma_i[t] + beta_i[t];
    const float p = bsum128(u * iv * pred_W[t], red);
    if (t == 0) out[b] = p + pred_b[0];
}

// ---------------- K6: KL final reduction ----------------
__global__ __launch_bounds__(256) void k6_kl(const float* __restrict__ klu,
                                             const float* __restrict__ kli,
                                             const float* __restrict__ msm,
                                             float* __restrict__ out) {
    __shared__ float red[4];
    const int t = threadIdx.x;
    float su = 0.f, si = 0.f, sm = 0.f;
    for (int b = t; b < B_; b += 256) {
        su += klu[b];
        si += kli[b];
        sm += msm[b];
    }
    su = wave_sum(su);
    si = wave_sum(si);
    sm = wave_sum(sm);
    __syncthreads();
    if ((t & 63) == 0) red[t >> 6] = su;
    __syncthreads();
    su = red[0] + red[1] + red[2] + red[3];
    __syncthreads();
    if ((t & 63) == 0) red[t >> 6] = si;
    __syncthreads();
    si = red[0] + red[1] + red[2] + red[3];
    __syncthreads();
    if ((t & 63) == 0) red[t >> 6] = sm;
    __syncthreads();
    sm = red[0] + red[1] + red[2] + red[3];
    if (t == 0) {
        const float inv = 1.f / (sm + 1e-8f);
        out[0] = 0.5f * (su * inv + si * inv);
    }
}

extern "C" void kernel_launch(void* const* d_in, const int* in_sizes, int n_in,
                              void* d_out, int out_size, void* d_ws, size_t ws_size,
                              hipStream_t stream) {
    const int* user_idx = (const int*)d_in[0];
    const int* item_idx = (const int*)d_in[1];
    const int* user_hist = (const int*)d_in[2];
    const float* user_embed = (const float*)d_in[3];
    const float* item_embed = (const float*)d_in[4];
    const float* W_i = (const float*)d_in[5];
    const float* W_h = (const float*)d_in[6];
    const float* Wq = (const float*)d_in[7];
    const float* Wk = (const float*)d_in[8];
    const float* v_attn = (const float*)d_in[9];
    const float* pred_W = (const float*)d_in[10];
    const float* pred_b = (const float*)d_in[11];
    const float* gamma_u = (const float*)d_in[12];
    const float* beta_u = (const float*)d_in[13];
    const float* gamma_i = (const float*)d_in[14];
    const float* beta_i = (const float*)d_in[15];
    const float* noise_u = (const float*)d_in[16];
    const float* noise_i = (const float*)d_in[17];
    float* out = (float*)d_out;

    char* ws = (char*)d_ws;
    size_t off = 0;
    auto alloc = [&](size_t bytes) -> void* {
        void* p = ws + off;
        off = (off + bytes + 255) & ~(size_t)255;
        return p;
    };
    short* Mbf    = (short*)alloc(128 * 128 * 2);
    short* item_bf = (short*)alloc((size_t)(NITEMS + 1) * 128 * 2);
    float* uid = (float*)alloc((size_t)B_ * 128 * 4);
    float* tid = (float*)alloc((size_t)B_ * 128 * 4);
    float* qu  = (float*)alloc((size_t)B_ * 128 * 4);
    float* qt  = (float*)alloc((size_t)B_ * 128 * 4);
    int* hg    = (int*)alloc((size_t)B_ * L_ * 4);
    float* mkf = (float*)alloc((size_t)B_ * L_ * 4);
    float* scu = (float*)alloc((size_t)B_ * L_ * 4);
    float* sci = (float*)alloc((size_t)B_ * L_ * 4);
    float* atu = (float*)alloc((size_t)B_ * L_ * 4);
    float* ati = (float*)alloc((size_t)B_ * L_ * 4);
    float* klu = (float*)alloc((size_t)B_ * 4);
    float* kli = (float*)alloc((size_t)B_ * 4);
    float* msm = (float*)alloc((size_t)B_ * 4);

    const int n8 = (NITEMS + 1) * 128 / 8;
    k0_cvt<<<(n8 + 255) / 256, 256, 0, stream>>>(item_embed, item_bf, n8);
    k1_M<<<128, 128, 0, stream>>>(Wk, W_h, Mbf);
    k2_prep<<<B_, 128, 0, stream>>>(user_idx, item_idx, user_hist, user_embed,
                                    item_embed, W_i, Wq, uid, tid, qu, qt, hg, mkf);
    k3_scores<<<(B_ * L_) / 128, 256, 0, stream>>>(Mbf, item_bf, hg, qu, qt, v_attn,
                                                   scu, sci);
    k4_softmax<<<B_ / 4, 256, 0, stream>>>(scu, sci, mkf, noise_u, noise_i, atu, ati,
                                           klu, kli, msm);
    k5_out<<<B_, 128, 0, stream>>>(atu, ati, hg, item_bf, W_h, uid, tid, gamma_u,
                                   beta_u, gamma_i, beta_i, pred_W, pred_b, out);
    k6_kl<<<1, 256, 0, stream>>>(klu, kli, msm, out + B_);
}